// Round 4
// baseline (282.436 us; speedup 1.0000x reference)
//
#include <hip/hip_runtime.h>
#include <cmath>

#define Bb 32
#define Ss 2048
#define Hh 768
#define Oo 768
#define Kk 64

// K1: one wave per (b,j) raw score (hidden_row . Wa[H:]); also zero aw_out.
// grid 512 x 256 (2048 waves).
__global__ __launch_bounds__(256) void scores_kernel(
    const float* __restrict__ hidden,
    const int*   __restrict__ idxs,
    const float* __restrict__ Wa,
    float* __restrict__ scores,   // ws[0:2048]
    float* __restrict__ aw_out)
{
    const int tid  = threadIdx.x;
    const int lane = tid & 63;
    const int wid  = blockIdx.x * 4 + (tid >> 6);   // 0..2047
    const int gid  = blockIdx.x * 256 + tid;

    // zero attention-weight output (B*S = 65536 floats = 16384 float4)
    if (gid < (Bb * Ss / 4))
        ((float4*)aw_out)[gid] = make_float4(0.f, 0.f, 0.f, 0.f);

    const int b = wid >> 6;
    const int j = wid & 63;
    const int t_idx = idxs[b * Kk + j];

    const float4* row4 = (const float4*)(hidden + ((size_t)b * Ss + t_idx) * Hh);
    const float4* wa4  = (const float4*)(Wa + Hh);
    float p = 0.f;
    #pragma unroll
    for (int t = 0; t < 3; ++t) {
        const float4 r = row4[lane + 64 * t];
        const float4 w = wa4[lane + 64 * t];
        p += r.x * w.x + r.y * w.y + r.z * w.z + r.w * w.w;
    }
    #pragma unroll
    for (int m = 32; m >= 1; m >>= 1) p += __shfl_xor(p, m);
    if (lane == 0) scores[wid] = p;
}

// K2: softmax (dedup'd) + aw scatter + pooled. grid = B*3 blocks x 256.
// block (b, hc): wave 0 computes the 64-slot softmax, then all 256 threads
// compute pooled[b, hc*256 + tid]. Gather of hidden happens exactly once.
__global__ __launch_bounds__(256) void softmax_pool_kernel(
    const float* __restrict__ hidden,
    const int*   __restrict__ idxs,
    const float* __restrict__ subj,
    const float* __restrict__ Wa,
    const float* __restrict__ ba,
    const float* __restrict__ scores,
    float* __restrict__ aw_out,
    float* __restrict__ pooled)   // ws[2048:2048+B*H]
{
    const int b   = blockIdx.x / 3;
    const int hc  = blockIdx.x % 3;
    const int tid = threadIdx.x;

    __shared__ float s_aw[Kk];
    __shared__ int   s_idx[Kk];

    if (tid < Kk) {
        const int j     = tid;
        const int myidx = idxs[b * Kk + j];
        s_idx[j] = myidx;

        // sconst = subj[b] . Wa[0:H] + ba (butterfly leaves sum in all lanes)
        const float4* s4  = (const float4*)(subj + b * Hh);
        const float4* wa4 = (const float4*)Wa;
        float p = 0.f;
        #pragma unroll
        for (int t = 0; t < 3; ++t) {
            const float4 r = s4[j + 64 * t];
            const float4 w = wa4[j + 64 * t];
            p += r.x * w.x + r.y * w.y + r.z * w.z + r.w * w.w;
        }
        #pragma unroll
        for (int m = 32; m >= 1; m >>= 1) p += __shfl_xor(p, m);
        const float sconst = p + ba[0];

        const int  previdx = __shfl_up(myidx, 1);
        const bool active  = (j == 0) || (myidx != previdx);

        float sc = active ? (scores[b * Kk + j] + sconst) : -3.0e38f;
        float mx = sc;
        #pragma unroll
        for (int m = 32; m >= 1; m >>= 1) mx = fmaxf(mx, __shfl_xor(mx, m));
        const float e = active ? expf(sc - mx) : 0.f;
        float sum = e;
        #pragma unroll
        for (int m = 32; m >= 1; m >>= 1) sum += __shfl_xor(sum, m);
        const float w = e / sum;              // duplicates get 0

        s_aw[j] = w;
        if (hc == 0 && active) aw_out[(size_t)b * Ss + myidx] = w;
    }
    __syncthreads();

    // pooled[b, h]: 64-term weighted sum of gathered rows (dupes weight 0)
    const int h = hc * 256 + tid;
    float acc = 0.f;
    #pragma unroll 8
    for (int j = 0; j < Kk; ++j)
        acc += s_aw[j] * hidden[((size_t)b * Ss + s_idx[j]) * Hh + h];
    pooled[b * Hh + h] = acc;
}

// K3: out[b,o] = tanh(pooled[b] . Wo[:,o] + bo[o])
// grid = 96 blocks x 256 threads. Block bc owns o-chunk of 8 and ALL 32 b:
// thread = (b = tid&31, og = tid>>5). Wo is read exactly once chip-wide
// (2.36 MB instead of 75 MB); pooled rows stream via float4 (L1/L2-hot).
__global__ __launch_bounds__(256) void gemm_tanh_kernel(
    const float* __restrict__ pooled,
    const float* __restrict__ Wo,
    const float* __restrict__ bo,
    float* __restrict__ out)
{
    const int bc = blockIdx.x;            // 0..95
    const int b  = threadIdx.x & 31;
    const int o  = bc * 8 + (threadIdx.x >> 5);

    const float4* p4 = (const float4*)(pooled + b * Hh);
    float a0 = 0.f, a1 = 0.f, a2 = 0.f, a3 = 0.f;
    #pragma unroll 4
    for (int i = 0; i < Hh / 4; ++i) {
        const float4 pv = p4[i];
        const int h = 4 * i;
        a0 = fmaf(pv.x, Wo[(h + 0) * Oo + o], a0);
        a1 = fmaf(pv.y, Wo[(h + 1) * Oo + o], a1);
        a2 = fmaf(pv.z, Wo[(h + 2) * Oo + o], a2);
        a3 = fmaf(pv.w, Wo[(h + 3) * Oo + o], a3);
    }
    out[b * Oo + o] = tanhf(a0 + a1 + a2 + a3 + bo[o]);
}

extern "C" void kernel_launch(void* const* d_in, const int* in_sizes, int n_in,
                              void* d_out, int out_size, void* d_ws, size_t ws_size,
                              hipStream_t stream) {
    const float* hidden = (const float*)d_in[0];
    const int*   idxs   = (const int*)d_in[1];
    const float* subj   = (const float*)d_in[2];
    const float* Wa     = (const float*)d_in[3];
    const float* ba     = (const float*)d_in[4];
    const float* Wo     = (const float*)d_in[5];
    const float* bo     = (const float*)d_in[6];

    float* out    = (float*)d_out;            // transformed: B*O floats
    float* aw_out = out + Bb * Oo;            // attention_weights: B*S floats
    float* scores = (float*)d_ws;             // [B*K]
    float* pooled = scores + Bb * Kk;         // [B*H]

    scores_kernel      <<<512, 256, 0, stream>>>(hidden, idxs, Wa, scores, aw_out);
    softmax_pool_kernel<<<Bb * 3, 256, 0, stream>>>(hidden, idxs, subj, Wa, ba,
                                                    scores, aw_out, pooled);
    gemm_tanh_kernel   <<<96, 256, 0, stream>>>(pooled, Wo, bo, out);
}